// Round 11
// baseline (197.011 us; speedup 1.0000x reference)
//
#include <hip/hip_runtime.h>
#include <hip/hip_bf16.h>
#include <math.h>

typedef __attribute__((ext_vector_type(8))) short short8;
typedef __attribute__((ext_vector_type(4))) float f32x4;
typedef __attribute__((ext_vector_type(4))) short short4v;
typedef __attribute__((ext_vector_type(2))) int int2v;

static __device__ __forceinline__ short f2bf(float f) {
    __hip_bfloat16 h = __float2bfloat16(f);
    return *reinterpret_cast<short*>(&h);
}
static __device__ __forceinline__ void store_out(float* p, float v) { *p = v; }
static __device__ __forceinline__ void store_out(short* p, float v) { *p = f2bf(v); }

#define GLL16(g, l) __builtin_amdgcn_global_load_lds( \
    (const __attribute__((address_space(1))) void*)(g), \
    (__attribute__((address_space(3))) void*)(l), 16, 0, 0)

#if __has_builtin(__builtin_amdgcn_exp2f)
#define EXP2(x) __builtin_amdgcn_exp2f(x)
#else
#define EXP2(x) exp2f(x)
#endif

// pack two f32 -> packed bf16 pair (low = a, high = b)
#if __has_builtin(__builtin_amdgcn_cvt_pk_bf16_f32)
typedef __attribute__((ext_vector_type(2))) __bf16 bf16x2;
static __device__ __forceinline__ int pack2bf(float a, float b) {
    bf16x2 r = __builtin_amdgcn_cvt_pk_bf16_f32(a, b);
    return __builtin_bit_cast(int, r);
}
#else
static __device__ __forceinline__ int pack2bf(float a, float b) {
    unsigned ua = __builtin_bit_cast(unsigned, a) + 0x8000u;
    unsigned ub = __builtin_bit_cast(unsigned, b) + 0x8000u;
    return (int)((ua >> 16) | (ub & 0xFFFF0000u));
}
#endif

// ---------------- fused prep: cast x -> bf16; transpose+cast both weights ----
static __device__ __forceinline__ void transpose_cast_tile(
    const float* __restrict__ W, short* __restrict__ Wt, int Kd, int N,
    int bx, int by)
{
    __shared__ float ts[32][33];
    const int c0 = bx * 32, r0 = by * 32;
    const int tx = threadIdx.x & 31, ty = threadIdx.x >> 5;   // ty 0..7
    #pragma unroll
    for (int e = 0; e < 4; ++e)
        ts[ty + e * 8][tx] = W[(size_t)(r0 + ty + e * 8) * N + c0 + tx];
    __syncthreads();
    #pragma unroll
    for (int e = 0; e < 4; ++e)
        Wt[(size_t)(c0 + ty + e * 8) * Kd + r0 + tx] = f2bf(ts[tx][ty + e * 8]);
}

__global__ __launch_bounds__(256) void prep_kernel(
    const float* __restrict__ x,      short* __restrict__ xb,    int nx,
    const float* __restrict__ W_qkv,  short* __restrict__ Wt1,
    const float* __restrict__ W_proj, short* __restrict__ Wt2,
    int C)
{
    const int nbx = nx / 1024;
    const int nb1 = (3 * C / 32) * (C / 32);
    int bid = blockIdx.x;
    if (bid < nbx) {
        int i = (bid * 256 + threadIdx.x) * 4;
        float4 v = *(const float4*)(x + i);
        short4v o = { f2bf(v.x), f2bf(v.y), f2bf(v.z), f2bf(v.w) };
        *(short4v*)(xb + i) = o;
        return;
    }
    bid -= nbx;
    if (bid < nb1) {
        const int nc = 3 * C / 32;
        transpose_cast_tile(W_qkv, Wt1, C, 3 * C, bid % nc, bid / nc);
        return;
    }
    bid -= nb1;
    {
        const int nc = C / 32;
        transpose_cast_tile(W_proj, Wt2, C, C, bid % nc, bid / nc);
    }
}

// ---------------- V transpose: qkv [B,K,3C] -> Vt [B,H,DH,K] (bf16) ----------------
__global__ __launch_bounds__(256) void vtrans_kernel(
    const short* __restrict__ qkvb, short* __restrict__ vt, int K, int C)
{
    __shared__ short Vs[64][72];
    const int k0 = blockIdx.x * 64, h = blockIdx.y, b = blockIdx.z;
    const size_t rs = (size_t)3 * C;
    const short* src = qkvb + (size_t)b * K * rs + 2 * C + h * 64;
    const int key = threadIdx.x >> 3, d0 = (threadIdx.x & 7) * 8;
    *(short8*)&Vs[key][d0]      = *(const short8*)(src + (size_t)(k0 + key) * rs + d0);
    *(short8*)&Vs[key + 32][d0] = *(const short8*)(src + (size_t)(k0 + key + 32) * rs + d0);
    __syncthreads();
    const int d = threadIdx.x >> 2, kc = threadIdx.x & 3;
    short* dst = vt + ((size_t)(b * 16 + h) * 64 + d) * K + k0 + kc * 16;
    short8 o0, o1;
    #pragma unroll
    for (int j = 0; j < 8; ++j) { o0[j] = Vs[kc * 16 + j][d]; o1[j] = Vs[kc * 16 + 8 + j][d]; }
    *(short8*)dst = o0;
    *(short8*)(dst + 8) = o1;
}

// ---------------- MFMA bf16 GEMM (m97 structure): C = A @ Bt^T + bias --------
// Columns c < qcols get an extra *qscale (folds softmax scale into Q).
#define GM 128
#define GN 128
#define GK 32

template <typename OutT>
__global__ __launch_bounds__(256) void gemm_mfma_kernel(
    const short* __restrict__ A, const short* __restrict__ Bt,
    const float* __restrict__ bias, OutT* __restrict__ C,
    int M, int N, int Kd, int qcols, float qscale)
{
    __shared__ __attribute__((aligned(16))) short As[GM * GK];
    __shared__ __attribute__((aligned(16))) short Bs[GN * GK];
    const int tid  = threadIdx.x;
    const int lane = tid & 63, w = tid >> 6;
    const int col  = lane & 15, quad = lane >> 4;
    const int wm = (w & 1) * 64, wn = (w >> 1) * 64;
    const int row0 = blockIdx.y * GM, col0 = blockIdx.x * GN;
    const float sc = (col0 < qcols) ? qscale : 1.f;

    const int sr = tid >> 2, scg = (tid & 3) * 8;
    const short* gA = A  + (size_t)(row0 + sr) * Kd + scg;
    const short* gB = Bt + (size_t)(col0 + sr) * Kd + scg;
    short* lA = As + sr * GK + scg;
    short* lB = Bs + sr * GK + scg;
    const size_t skip = (size_t)64 * Kd;

    f32x4 acc[4][4] = {};
    for (int k0 = 0; k0 < Kd; k0 += GK) {
        __syncthreads();
        GLL16(gA,        lA);
        GLL16(gA + skip, lA + 64 * GK);
        GLL16(gB,        lB);
        GLL16(gB + skip, lB + 64 * GK);
        gA += GK; gB += GK;
        __syncthreads();

        short8 aF[4], bF[4];
        #pragma unroll
        for (int mt = 0; mt < 4; ++mt)
            aF[mt] = *(const short8*)&As[(wm + mt * 16 + col) * GK + quad * 8];
        #pragma unroll
        for (int nt = 0; nt < 4; ++nt)
            bF[nt] = *(const short8*)&Bs[(wn + nt * 16 + col) * GK + quad * 8];
        #pragma unroll
        for (int mt = 0; mt < 4; ++mt)
            #pragma unroll
            for (int nt = 0; nt < 4; ++nt)
                acc[mt][nt] = __builtin_amdgcn_mfma_f32_16x16x32_bf16(aF[mt], bF[nt], acc[mt][nt], 0, 0, 0);
    }

    #pragma unroll
    for (int mt = 0; mt < 4; ++mt)
        #pragma unroll
        for (int i = 0; i < 4; ++i) {
            const size_t r = row0 + wm + mt * 16 + quad * 4 + i;
            #pragma unroll
            for (int nt = 0; nt < 4; ++nt) {
                const int c = col0 + wn + nt * 16 + col;
                store_out(&C[r * N + c], (acc[mt][nt][i] + bias[c]) * sc);
            }
        }
}

// ---------------- MFMA flash attention — split-K + cross-chunk prefetch -----
// Block = 4 waves, one 64-q tile at a time (pair-balanced: tile g then 31-g).
// 32-key chunks; wave w owns chunks ci = w mod 4, staged into PRIVATE
// double-buffered LDS (K 4x520 + V 4x520 shorts per buf). Prefetch: issue
// chunk i+1's 8 global_load_lds, s_waitcnt vmcnt(8) for chunk i (oldest-first
// drain, m135) -> L2 latency hidden; NO __syncthreads in the K loop.
// Fixed-shift softmax (Q pre-scaled by scale*log2e in GEMM1): p = exp2(s),
// associative over keys; per-wave partial O/L reduced once per tile via LDS.
// Row-sums ride the MFMA pipe (ones-column fragment). 2048 waves = 8/CU;
// LDS 71.7 KB -> 2 blocks/CU.
#define DH 64

__global__ __launch_bounds__(256, 2) void flash_mfma_kernel(
    const short* __restrict__ qkvb,   // bf16 [B,K,3C] (Q pre-scaled)
    const short* __restrict__ vt,     // bf16 [B,H,DH,K]
    short* __restrict__ y,            // bf16 [B,K,C]
    int K, int C)
{
    // per wave: [K buf0 2080][V buf0 2080][K buf1 2080][V buf1 2080] = 8320 sh
    // 4 waves staging = 33280 sh; Pt 4 x 16 x 40 = 2560 sh. total 35840 sh = 71.7 KB
    __shared__ __attribute__((aligned(16))) short smem[35840];

    const int tid  = threadIdx.x;
    const int lane = tid & 63, w = tid >> 6;
    const int col  = lane & 15, quad = lane >> 4;

    short* Wreg = smem + w * 8320;
    short* Ptw  = smem + 33280 + w * 640;
    float* Or   = (float*)smem;            // 64 x 68 f32 (17.4 KB) overlay

    const int cmb = blockIdx.x & 31;       // b*16+h  (XCD-local: idx%8 tracks h)
    const int g   = blockIdx.x >> 5;       // pair index 0..15
    const int b   = cmb >> 4, h = cmb & 15;

    short8 bOnes;                          // L = P @ ones-column = rowsum
    #pragma unroll
    for (int j = 0; j < 8; ++j) bOnes[j] = (col == 0) ? (short)0x3F80 : (short)0;

    const size_t rs = (size_t)3 * C;
    const short* qbase = qkvb + (size_t)b * K * rs + h * DH;
    const short* kbase = qbase + C;
    const short* vbase = vt + (size_t)(b * 16 + h) * DH * K;

    // staging lane maps (fixed): K row = (lane>>3)*4 + c2, dh off (lane&7)*8
    //                            V d-row = c2*16 + (lane>>2), k off (lane&3)*8
    const int krow = (lane >> 3) * 4, koff = (lane & 7) * 8;
    const int vrow = lane >> 2,       voff = (lane & 3) * 8;
    const int loff = lane * 8;

    auto stage = [&](int ci, int buf) {
        const int kc = ci * 32;
        short* Kb = Wreg + buf * 4160;
        short* Vb = Kb + 2080;
        #pragma unroll
        for (int c2 = 0; c2 < 4; ++c2)
            GLL16(kbase + (size_t)(kc + krow + c2) * rs + koff, Kb + c2 * 520 + loff);
        #pragma unroll
        for (int c2 = 0; c2 < 4; ++c2)
            GLL16(vbase + (size_t)(c2 * 16 + vrow) * K + kc + voff, Vb + c2 * 520 + loff);
    };

    auto run = [&](int T) {
        const int t0 = T * 64;
        const int NC = 2 * T + 2;          // 32-key chunks in this tile

        short8 aQ[4][2];
        #pragma unroll
        for (int qg = 0; qg < 4; ++qg) {
            const short* qp = qbase + (size_t)(t0 + qg * 16 + col) * rs;
            aQ[qg][0] = *(const short8*)(qp + quad * 8);
            aQ[qg][1] = *(const short8*)(qp + 32 + quad * 8);
        }
        f32x4 O[4][4] = {};
        f32x4 L4[4] = {};

        int ci = w, buf = 0;
        if (ci < NC) stage(ci, 0);
        for (; ci < NC; ci += 4) {
            const int kc = ci * 32;
            const int nci = ci + 4;
            if (nci < NC) {
                stage(nci, buf ^ 1);
                asm volatile("s_waitcnt vmcnt(8)" ::: "memory");  // chunk ci landed
            } else {
                asm volatile("s_waitcnt vmcnt(0)" ::: "memory");
            }
            const short* Kb = Wreg + buf * 4160;
            const short* Vb = Kb + 2080;

            // fragments read ONCE, reused by all 4 q-groups
            short8 bK[2][2], bV[4];
            #pragma unroll
            for (int nb = 0; nb < 2; ++nb) {           // key = col*2+nb
                const int kl = col * 2 + nb;
                const int ka = (kl & 3) * 520 + (kl >> 2) * 64 + quad * 8;
                bK[nb][0] = *(const short8*)&Kb[ka];
                bK[nb][1] = *(const short8*)&Kb[ka + 32];
            }
            #pragma unroll
            for (int db = 0; db < 4; ++db)             // d = db*16+col
                bV[db] = *(const short8*)&Vb[db * 520 + col * 32 + quad * 8];

            #pragma unroll
            for (int qg = 0; qg < 4; ++qg) {
                const int qb = t0 + qg * 16;
                f32x4 S[2] = {};
                #pragma unroll
                for (int nb = 0; nb < 2; ++nb) {
                    S[nb] = __builtin_amdgcn_mfma_f32_16x16x32_bf16(aQ[qg][0], bK[nb][0], S[nb], 0, 0, 0);
                    S[nb] = __builtin_amdgcn_mfma_f32_16x16x32_bf16(aQ[qg][1], bK[nb][1], S[nb], 0, 0, 0);
                }
                if (kc + 31 <= qb) {        // fully unmasked for this q-group
                    #pragma unroll
                    for (int i = 0; i < 4; ++i)
                        *(int*)&Ptw[(quad * 4 + i) * 40 + col * 2] =
                            pack2bf(EXP2(S[0][i]), EXP2(S[1][i]));
                } else {
                    const int kg = kc + col * 2;
                    #pragma unroll
                    for (int i = 0; i < 4; ++i) {
                        const int q = qb + quad * 4 + i;
                        float s0 = (kg + 0 <= q) ? S[0][i] : -INFINITY;
                        float s1 = (kg + 1 <= q) ? S[1][i] : -INFINITY;
                        *(int*)&Ptw[(quad * 4 + i) * 40 + col * 2] =
                            pack2bf(EXP2(s0), EXP2(s1));
                    }
                }
                asm volatile("s_waitcnt lgkmcnt(0)" ::: "memory");  // P visible in-wave
                short8 aP = *(const short8*)&Ptw[col * 40 + quad * 8];
                #pragma unroll
                for (int db = 0; db < 4; ++db)
                    O[qg][db] = __builtin_amdgcn_mfma_f32_16x16x32_bf16(aP, bV[db], O[qg][db], 0, 0, 0);
                L4[qg] = __builtin_amdgcn_mfma_f32_16x16x32_bf16(aP, bOnes, L4[qg], 0, 0, 0);
            }
            buf ^= 1;
        }

        // ---- cross-wave reduction of partial O / L ----
        __syncthreads();
        for (int ww = 0; ww < 4; ++ww) {
            if (w == ww) {
                #pragma unroll
                for (int qg = 0; qg < 4; ++qg)
                    #pragma unroll
                    for (int i = 0; i < 4; ++i) {
                        const int row = qg * 16 + quad * 4 + i;
                        #pragma unroll
                        for (int db = 0; db < 4; ++db) {
                            float v = O[qg][db][i];
                            if (ww == 0) Or[row * 68 + db * 16 + col] = v;
                            else         Or[row * 68 + db * 16 + col] += v;
                        }
                        if (col == 0) {
                            if (ww == 0) Or[row * 68 + 64] = L4[qg][i];
                            else         Or[row * 68 + 64] += L4[qg][i];
                        }
                    }
            }
            __syncthreads();
        }

        // ---- normalize + store: wave w -> rows [w*16, w*16+16) ----
        #pragma unroll
        for (int rstep = 0; rstep < 4; ++rstep) {
            const int row = w * 16 + rstep * 4 + quad;
            f32x4 ov = *(const f32x4*)&Or[row * 68 + col * 4];
            const float inv = 1.f / Or[row * 68 + 64];
            int2v o2 = { pack2bf(ov[0] * inv, ov[1] * inv),
                         pack2bf(ov[2] * inv, ov[3] * inv) };
            *(int2v*)(y + ((size_t)b * K + t0 + row) * C + h * DH + col * 4) = o2;
        }
        __syncthreads();   // protect Or before next tile restages
    };

    run(g);
    run(31 - g);
}

// ------------------------------- launch -------------------------------------
extern "C" void kernel_launch(void* const* d_in, const int* in_sizes, int n_in,
                              void* d_out, int out_size, void* d_ws, size_t ws_size,
                              hipStream_t stream)
{
    const float* x      = (const float*)d_in[0];
    const float* W_qkv  = (const float*)d_in[1];
    const float* b_qkv  = (const float*)d_in[2];
    const float* W_proj = (const float*)d_in[3];
    const float* b_proj = (const float*)d_in[4];

    const int B = 2, K = 2048, C = 1024, H = 16;
    const int M = B * K;   // 4096
    const float C2 = 0.18033688f;   // (1/sqrt(64)) * log2(e)

    char* ws = (char*)d_ws;
    short* xb    = (short*)ws;  ws += (size_t)M * C * 2;
    short* Wt1   = (short*)ws;  ws += (size_t)3 * C * C * 2;
    short* Wt2   = (short*)ws;  ws += (size_t)C * C * 2;
    short* qkvb  = (short*)ws;  ws += (size_t)M * 3 * C * 2;
    short* yb    = (short*)ws;  ws += (size_t)M * C * 2;
    short* vtb   = (short*)ws;

    // prep (fused): cast x + transpose both weights
    const int nbx = (M * C) / 1024;
    const int nb1 = (3 * C / 32) * (C / 32);
    const int nb2 = (C / 32) * (C / 32);
    prep_kernel<<<nbx + nb1 + nb2, 256, 0, stream>>>(x, xb, M * C, W_qkv, Wt1, W_proj, Wt2, C);

    // 1) qkv = x @ W_qkv + b_qkv  (bf16 out; Q columns pre-scaled by C2)
    dim3 g1((3 * C) / GN, M / GM);
    gemm_mfma_kernel<short><<<g1, 256, 0, stream>>>(xb, Wt1, b_qkv, qkvb, M, 3 * C, C, C, C2);

    // 1b) V transpose for flash B-fragments
    dim3 gv(K / 64, H, B);
    vtrans_kernel<<<gv, 256, 0, stream>>>(qkvb, vtb, K, C);

    // 2) flash attention -> yb (bf16); 1-D grid: idx = pair*32 + (b*16+h)
    const int NPAIR = (K / 64) / 2;   // 16
    flash_mfma_kernel<<<dim3(NPAIR * 32), 256, 0, stream>>>(qkvb, vtb, yb, K, C);

    // 3) out = y @ W_proj + b_proj (fp32 out)
    dim3 g3(C / GN, M / GM);
    gemm_mfma_kernel<float><<<g3, 256, 0, stream>>>(yb, Wt2, b_proj, (float*)d_out, M, C, C, 0, 1.f);
}

// Round 12
// 192.710 us; speedup vs baseline: 1.0223x; 1.0223x over previous
//
#include <hip/hip_runtime.h>
#include <hip/hip_bf16.h>
#include <math.h>

typedef __attribute__((ext_vector_type(8))) short short8;
typedef __attribute__((ext_vector_type(4))) float f32x4;
typedef __attribute__((ext_vector_type(4))) short short4v;
typedef __attribute__((ext_vector_type(2))) int int2v;

static __device__ __forceinline__ short f2bf(float f) {
    __hip_bfloat16 h = __float2bfloat16(f);
    return *reinterpret_cast<short*>(&h);
}
static __device__ __forceinline__ void store_out(float* p, float v) { *p = v; }
static __device__ __forceinline__ void store_out(short* p, float v) { *p = f2bf(v); }

#define GLL16(g, l) __builtin_amdgcn_global_load_lds( \
    (const __attribute__((address_space(1))) void*)(g), \
    (__attribute__((address_space(3))) void*)(l), 16, 0, 0)

#if __has_builtin(__builtin_amdgcn_exp2f)
#define EXP2(x) __builtin_amdgcn_exp2f(x)
#else
#define EXP2(x) exp2f(x)
#endif

// pack two f32 -> packed bf16 pair (low = a, high = b)
#if __has_builtin(__builtin_amdgcn_cvt_pk_bf16_f32)
typedef __attribute__((ext_vector_type(2))) __bf16 bf16x2;
static __device__ __forceinline__ int pack2bf(float a, float b) {
    bf16x2 r = __builtin_amdgcn_cvt_pk_bf16_f32(a, b);
    return __builtin_bit_cast(int, r);
}
#else
static __device__ __forceinline__ int pack2bf(float a, float b) {
    unsigned ua = __builtin_bit_cast(unsigned, a) + 0x8000u;
    unsigned ub = __builtin_bit_cast(unsigned, b) + 0x8000u;
    return (int)((ua >> 16) | (ub & 0xFFFF0000u));
}
#endif

// ---------------- fused prep: cast x -> bf16; transpose+cast both weights ----
static __device__ __forceinline__ void transpose_cast_tile(
    const float* __restrict__ W, short* __restrict__ Wt, int Kd, int N,
    int bx, int by)
{
    __shared__ float ts[32][33];
    const int c0 = bx * 32, r0 = by * 32;
    const int tx = threadIdx.x & 31, ty = threadIdx.x >> 5;   // ty 0..7
    #pragma unroll
    for (int e = 0; e < 4; ++e)
        ts[ty + e * 8][tx] = W[(size_t)(r0 + ty + e * 8) * N + c0 + tx];
    __syncthreads();
    #pragma unroll
    for (int e = 0; e < 4; ++e)
        Wt[(size_t)(c0 + ty + e * 8) * Kd + r0 + tx] = f2bf(ts[tx][ty + e * 8]);
}

__global__ __launch_bounds__(256) void prep_kernel(
    const float* __restrict__ x,      short* __restrict__ xb,    int nx,
    const float* __restrict__ W_qkv,  short* __restrict__ Wt1,
    const float* __restrict__ W_proj, short* __restrict__ Wt2,
    int C)
{
    const int nbx = nx / 1024;
    const int nb1 = (3 * C / 32) * (C / 32);
    int bid = blockIdx.x;
    if (bid < nbx) {
        int i = (bid * 256 + threadIdx.x) * 4;
        float4 v = *(const float4*)(x + i);
        short4v o = { f2bf(v.x), f2bf(v.y), f2bf(v.z), f2bf(v.w) };
        *(short4v*)(xb + i) = o;
        return;
    }
    bid -= nbx;
    if (bid < nb1) {
        const int nc = 3 * C / 32;
        transpose_cast_tile(W_qkv, Wt1, C, 3 * C, bid % nc, bid / nc);
        return;
    }
    bid -= nb1;
    {
        const int nc = C / 32;
        transpose_cast_tile(W_proj, Wt2, C, C, bid % nc, bid / nc);
    }
}

// ---------------- V transpose: qkv [B,K,3C] -> Vt [B,H,DH,K] (bf16) ----------------
__global__ __launch_bounds__(256) void vtrans_kernel(
    const short* __restrict__ qkvb, short* __restrict__ vt, int K, int C)
{
    __shared__ short Vs[64][72];
    const int k0 = blockIdx.x * 64, h = blockIdx.y, b = blockIdx.z;
    const size_t rs = (size_t)3 * C;
    const short* src = qkvb + (size_t)b * K * rs + 2 * C + h * 64;
    const int key = threadIdx.x >> 3, d0 = (threadIdx.x & 7) * 8;
    *(short8*)&Vs[key][d0]      = *(const short8*)(src + (size_t)(k0 + key) * rs + d0);
    *(short8*)&Vs[key + 32][d0] = *(const short8*)(src + (size_t)(k0 + key + 32) * rs + d0);
    __syncthreads();
    const int d = threadIdx.x >> 2, kc = threadIdx.x & 3;
    short* dst = vt + ((size_t)(b * 16 + h) * 64 + d) * K + k0 + kc * 16;
    short8 o0, o1;
    #pragma unroll
    for (int j = 0; j < 8; ++j) { o0[j] = Vs[kc * 16 + j][d]; o1[j] = Vs[kc * 16 + 8 + j][d]; }
    *(short8*)dst = o0;
    *(short8*)(dst + 8) = o1;
}

// ---------------- MFMA bf16 GEMM (m97 structure): C = A @ Bt^T + bias --------
// Columns c < qcols get an extra *qscale (folds softmax scale into Q).
#define GM 128
#define GN 128
#define GK 32

template <typename OutT>
__global__ __launch_bounds__(256) void gemm_mfma_kernel(
    const short* __restrict__ A, const short* __restrict__ Bt,
    const float* __restrict__ bias, OutT* __restrict__ C,
    int M, int N, int Kd, int qcols, float qscale)
{
    __shared__ __attribute__((aligned(16))) short As[GM * GK];
    __shared__ __attribute__((aligned(16))) short Bs[GN * GK];
    const int tid  = threadIdx.x;
    const int lane = tid & 63, w = tid >> 6;
    const int col  = lane & 15, quad = lane >> 4;
    const int wm = (w & 1) * 64, wn = (w >> 1) * 64;
    const int row0 = blockIdx.y * GM, col0 = blockIdx.x * GN;
    const float sc = (col0 < qcols) ? qscale : 1.f;

    const int sr = tid >> 2, scg = (tid & 3) * 8;
    const short* gA = A  + (size_t)(row0 + sr) * Kd + scg;
    const short* gB = Bt + (size_t)(col0 + sr) * Kd + scg;
    short* lA = As + sr * GK + scg;
    short* lB = Bs + sr * GK + scg;
    const size_t skip = (size_t)64 * Kd;

    f32x4 acc[4][4] = {};
    for (int k0 = 0; k0 < Kd; k0 += GK) {
        __syncthreads();
        GLL16(gA,        lA);
        GLL16(gA + skip, lA + 64 * GK);
        GLL16(gB,        lB);
        GLL16(gB + skip, lB + 64 * GK);
        gA += GK; gB += GK;
        __syncthreads();

        short8 aF[4], bF[4];
        #pragma unroll
        for (int mt = 0; mt < 4; ++mt)
            aF[mt] = *(const short8*)&As[(wm + mt * 16 + col) * GK + quad * 8];
        #pragma unroll
        for (int nt = 0; nt < 4; ++nt)
            bF[nt] = *(const short8*)&Bs[(wn + nt * 16 + col) * GK + quad * 8];
        #pragma unroll
        for (int mt = 0; mt < 4; ++mt)
            #pragma unroll
            for (int nt = 0; nt < 4; ++nt)
                acc[mt][nt] = __builtin_amdgcn_mfma_f32_16x16x32_bf16(aF[mt], bF[nt], acc[mt][nt], 0, 0, 0);
    }

    #pragma unroll
    for (int mt = 0; mt < 4; ++mt)
        #pragma unroll
        for (int i = 0; i < 4; ++i) {
            const size_t r = row0 + wm + mt * 16 + quad * 4 + i;
            #pragma unroll
            for (int nt = 0; nt < 4; ++nt) {
                const int c = col0 + wn + nt * 16 + col;
                store_out(&C[r * N + c], (acc[mt][nt][i] + bias[c]) * sc);
            }
        }
}

// ---------------- MFMA flash attention — split-K, unserialized qg chains ----
// Block = 4 waves, one 64-q tile at a time (pair-balanced: tile g then 31-g).
// 32-key chunks; wave w owns chunks ci = w mod 4, staged into PRIVATE
// single-buffer LDS (K 4x520 + V 4x520 shorts). Each of the 4 q-groups has
// its OWN P buffer and NO inline lgkmcnt barriers — the compiler tracks the
// ds_write->ds_read dependency per buffer and can software-pipeline the four
// independent chains (S-MFMA / exp2 / P-roundtrip / PV-MFMA). vmcnt(0) after
// global_load_lds stays (async LDS writes have no compiler dataflow edge).
// Fixed-shift softmax (Q pre-scaled by scale*log2e in GEMM1): p = exp2(s);
// row-sums ride the MFMA pipe (ones-column fragment). Pairwise cross-wave
// reduction (A/B regions). 2048 waves = 8/CU; LDS 53.8 KB -> 2 blocks/CU.
#define DH 64

__global__ __launch_bounds__(256, 2) void flash_mfma_kernel(
    const short* __restrict__ qkvb,   // bf16 [B,K,3C] (Q pre-scaled)
    const short* __restrict__ vt,     // bf16 [B,H,DH,K]
    short* __restrict__ y,            // bf16 [B,K,C]
    int K, int C)
{
    // staging: 4 waves x (K 2080 + V 2080) = 16640 sh (33.3 KB)
    // P: 16 bufs (wave,qg) x 16 x 40 = 10240 sh (20.5 KB)   total 26880 sh = 53.8 KB
    __shared__ __attribute__((aligned(16))) short smem[26880];

    const int tid  = threadIdx.x;
    const int lane = tid & 63, w = tid >> 6;
    const int col  = lane & 15, quad = lane >> 4;

    short* Kb = smem + w * 4160;
    short* Vb = Kb + 2080;
    short* Pw = smem + 16640 + w * 2560;   // 4 qg bufs x 640 sh

    const int cmb = blockIdx.x & 31;       // b*16+h  (XCD-local: idx%8 tracks h)
    const int g   = blockIdx.x >> 5;       // pair index 0..15
    const int b   = cmb >> 4, h = cmb & 15;

    short8 bOnes;                          // L = P @ ones-column = rowsum
    #pragma unroll
    for (int j = 0; j < 8; ++j) bOnes[j] = (col == 0) ? (short)0x3F80 : (short)0;

    const size_t rs = (size_t)3 * C;
    const short* qbase = qkvb + (size_t)b * K * rs + h * DH;
    const short* kbase = qbase + C;
    const short* vbase = vt + (size_t)(b * 16 + h) * DH * K;

    // staging lane maps: K row = (lane>>3)*4 + c2, dh off (lane&7)*8
    //                    V d-row = c2*16 + (lane>>2), k off (lane&3)*8
    const int krow = (lane >> 3) * 4, koff = (lane & 7) * 8;
    const int vrow = lane >> 2,       voff = (lane & 3) * 8;
    const int loff = lane * 8;

    auto run = [&](int T) {
        const int t0 = T * 64;
        const int NC = 2 * T + 2;          // 32-key chunks in this tile

        short8 aQ[4][2];
        #pragma unroll
        for (int qg = 0; qg < 4; ++qg) {
            const short* qp = qbase + (size_t)(t0 + qg * 16 + col) * rs;
            aQ[qg][0] = *(const short8*)(qp + quad * 8);
            aQ[qg][1] = *(const short8*)(qp + 32 + quad * 8);
        }
        f32x4 O[4][4] = {};
        f32x4 L4[4] = {};

        for (int ci = w; ci < NC; ci += 4) {
            const int kc = ci * 32;
            // ---- stage this wave's chunk (8 x 1KB) ----
            #pragma unroll
            for (int c2 = 0; c2 < 4; ++c2)
                GLL16(kbase + (size_t)(kc + krow + c2) * rs + koff, Kb + c2 * 520 + loff);
            #pragma unroll
            for (int c2 = 0; c2 < 4; ++c2)
                GLL16(vbase + (size_t)(c2 * 16 + vrow) * K + kc + voff, Vb + c2 * 520 + loff);
            asm volatile("s_waitcnt vmcnt(0)" ::: "memory");

            // fragments read ONCE, reused by all 4 q-groups
            short8 bK[2][2], bV[4];
            #pragma unroll
            for (int nb = 0; nb < 2; ++nb) {           // key = col*2+nb
                const int kl = col * 2 + nb;
                const int ka = (kl & 3) * 520 + (kl >> 2) * 64 + quad * 8;
                bK[nb][0] = *(const short8*)&Kb[ka];
                bK[nb][1] = *(const short8*)&Kb[ka + 32];
            }
            #pragma unroll
            for (int db = 0; db < 4; ++db)             // d = db*16+col
                bV[db] = *(const short8*)&Vb[db * 520 + col * 32 + quad * 8];

            #pragma unroll
            for (int qg = 0; qg < 4; ++qg) {
                const int qb = t0 + qg * 16;
                short* Ptq = Pw + qg * 640;            // private per (wave,qg)
                f32x4 S[2] = {};
                #pragma unroll
                for (int nb = 0; nb < 2; ++nb) {
                    S[nb] = __builtin_amdgcn_mfma_f32_16x16x32_bf16(aQ[qg][0], bK[nb][0], S[nb], 0, 0, 0);
                    S[nb] = __builtin_amdgcn_mfma_f32_16x16x32_bf16(aQ[qg][1], bK[nb][1], S[nb], 0, 0, 0);
                }
                if (kc + 31 <= qb) {        // fully unmasked for this q-group
                    #pragma unroll
                    for (int i = 0; i < 4; ++i)
                        *(int*)&Ptq[(quad * 4 + i) * 40 + col * 2] =
                            pack2bf(EXP2(S[0][i]), EXP2(S[1][i]));
                } else {
                    const int kg = kc + col * 2;
                    #pragma unroll
                    for (int i = 0; i < 4; ++i) {
                        const int q = qb + quad * 4 + i;
                        float s0 = (kg + 0 <= q) ? S[0][i] : -INFINITY;
                        float s1 = (kg + 1 <= q) ? S[1][i] : -INFINITY;
                        *(int*)&Ptq[(quad * 4 + i) * 40 + col * 2] =
                            pack2bf(EXP2(s0), EXP2(s1));
                    }
                }
                // compiler inserts the minimal lgkmcnt for this buffer's RAW
                short8 aP = *(const short8*)&Ptq[col * 40 + quad * 8];
                #pragma unroll
                for (int db = 0; db < 4; ++db)
                    O[qg][db] = __builtin_amdgcn_mfma_f32_16x16x32_bf16(aP, bV[db], O[qg][db], 0, 0, 0);
                L4[qg] = __builtin_amdgcn_mfma_f32_16x16x32_bf16(aP, bOnes, L4[qg], 0, 0, 0);
            }
        }

        // ---- pairwise cross-wave reduction: w0->A, w1->B; w2+=A, w3+=B ----
        float* OrA = (float*)smem;               // 64 x 68 f32
        float* OrB = OrA + 64 * 68;
        __syncthreads();
        if (w < 2) {
            float* R = (w == 0) ? OrA : OrB;
            #pragma unroll
            for (int qg = 0; qg < 4; ++qg)
                #pragma unroll
                for (int i = 0; i < 4; ++i) {
                    const int row = qg * 16 + quad * 4 + i;
                    #pragma unroll
                    for (int db = 0; db < 4; ++db)
                        R[row * 68 + db * 16 + col] = O[qg][db][i];
                    if (col == 0) R[row * 68 + 64] = L4[qg][i];
                }
        }
        __syncthreads();
        if (w >= 2) {
            float* R = (w == 2) ? OrA : OrB;
            #pragma unroll
            for (int qg = 0; qg < 4; ++qg)
                #pragma unroll
                for (int i = 0; i < 4; ++i) {
                    const int row = qg * 16 + quad * 4 + i;
                    #pragma unroll
                    for (int db = 0; db < 4; ++db)
                        R[row * 68 + db * 16 + col] += O[qg][db][i];
                    if (col == 0) R[row * 68 + 64] += L4[qg][i];
                }
        }
        __syncthreads();

        // ---- combine A+B, normalize, store: wave w -> rows [w*16, w*16+16) ----
        #pragma unroll
        for (int rstep = 0; rstep < 4; ++rstep) {
            const int row = w * 16 + rstep * 4 + quad;
            f32x4 oa = *(const f32x4*)&OrA[row * 68 + col * 4];
            f32x4 ob = *(const f32x4*)&OrB[row * 68 + col * 4];
            const float inv = 1.f / (OrA[row * 68 + 64] + OrB[row * 68 + 64]);
            int2v o2 = { pack2bf((oa[0] + ob[0]) * inv, (oa[1] + ob[1]) * inv),
                         pack2bf((oa[2] + ob[2]) * inv, (oa[3] + ob[3]) * inv) };
            *(int2v*)(y + ((size_t)b * K + t0 + row) * C + h * DH + col * 4) = o2;
        }
        __syncthreads();   // protect Or before next tile restages
    };

    run(g);
    run(31 - g);
}

// ------------------------------- launch -------------------------------------
extern "C" void kernel_launch(void* const* d_in, const int* in_sizes, int n_in,
                              void* d_out, int out_size, void* d_ws, size_t ws_size,
                              hipStream_t stream)
{
    const float* x      = (const float*)d_in[0];
    const float* W_qkv  = (const float*)d_in[1];
    const float* b_qkv  = (const float*)d_in[2];
    const float* W_proj = (const float*)d_in[3];
    const float* b_proj = (const float*)d_in[4];

    const int B = 2, K = 2048, C = 1024, H = 16;
    const int M = B * K;   // 4096
    const float C2 = 0.18033688f;   // (1/sqrt(64)) * log2(e)

    char* ws = (char*)d_ws;
    short* xb    = (short*)ws;  ws += (size_t)M * C * 2;
    short* Wt1   = (short*)ws;  ws += (size_t)3 * C * C * 2;
    short* Wt2   = (short*)ws;  ws += (size_t)C * C * 2;
    short* qkvb  = (short*)ws;  ws += (size_t)M * 3 * C * 2;
    short* yb    = (short*)ws;  ws += (size_t)M * C * 2;
    short* vtb   = (short*)ws;

    // prep (fused): cast x + transpose both weights
    const int nbx = (M * C) / 1024;
    const int nb1 = (3 * C / 32) * (C / 32);
    const int nb2 = (C / 32) * (C / 32);
    prep_kernel<<<nbx + nb1 + nb2, 256, 0, stream>>>(x, xb, M * C, W_qkv, Wt1, W_proj, Wt2, C);

    // 1) qkv = x @ W_qkv + b_qkv  (bf16 out; Q columns pre-scaled by C2)
    dim3 g1((3 * C) / GN, M / GM);
    gemm_mfma_kernel<short><<<g1, 256, 0, stream>>>(xb, Wt1, b_qkv, qkvb, M, 3 * C, C, C, C2);

    // 1b) V transpose for flash B-fragments
    dim3 gv(K / 64, H, B);
    vtrans_kernel<<<gv, 256, 0, stream>>>(qkvb, vtb, K, C);

    // 2) flash attention -> yb (bf16); 1-D grid: idx = pair*32 + (b*16+h)
    const int NPAIR = (K / 64) / 2;   // 16
    flash_mfma_kernel<<<dim3(NPAIR * 32), 256, 0, stream>>>(qkvb, vtb, yb, K, C);

    // 3) out = y @ W_proj + b_proj (fp32 out)
    dim3 g3(C / GN, M / GM);
    gemm_mfma_kernel<float><<<g3, 256, 0, stream>>>(yb, Wt2, b_proj, (float*)d_out, M, C, C, 0, 1.f);
}